// Round 1
// baseline (366.883 us; speedup 1.0000x reference)
//
#include <hip/hip_runtime.h>

#define NB 8
#define CHW 6300
#define TT 500
#define OUT 128
#define KS 8
#define KC 800
#define KSTEP 32

// ---------------- Kernel 1: transpose W[OUT][CHW] -> Wt[CHW][OUT] ----------------
__global__ __launch_bounds__(256) void transposeW(const float* __restrict__ W,
                                                  float* __restrict__ Wt) {
    __shared__ float tile[32][33];
    int bc = blockIdx.x * 32;           // c base
    int bo = blockIdx.y * 32;           // o base
    int tx = threadIdx.x;               // 0..31
    int ty = threadIdx.y;               // 0..7
#pragma unroll
    for (int k = 0; k < 4; k++) {
        int o = bo + ty + k * 8;
        int c = bc + tx;
        float v = (c < CHW) ? W[(size_t)o * CHW + c] : 0.f;
        tile[ty + k * 8][tx] = v;
    }
    __syncthreads();
#pragma unroll
    for (int k = 0; k < 4; k++) {
        int c = bc + ty + k * 8;
        int o = bo + tx;
        if (c < CHW) Wt[(size_t)c * OUT + o] = tile[tx][ty + k * 8];
    }
}

// ---------------- Kernel 2: split-K projection v[ks][t][n][o] = x[n][c][t]*Wt[c][o] ----
__global__ __launch_bounds__(256) void proj(const float* __restrict__ x,
                                            const float* __restrict__ Wt,
                                            float* __restrict__ vp) {
    const int tt = blockIdx.x;          // t tile 0..7
    const int n  = blockIdx.y;          // 0..7
    const int ks = blockIdx.z;          // 0..7
    const int t0 = tt * 64;
    const int kbeg = ks * KC;
    const int kend = min(kbeg + KC, CHW);

    __shared__ float xs[KSTEP][64];
    __shared__ float wsm[KSTEP][OUT];

    const int tid = threadIdx.x;
    const int ti = tid >> 4;            // 0..15 -> t = t0 + ti*4 + i
    const int oj = tid & 15;            // 0..15 -> o = oj*8 + j

    float acc[4][8];
#pragma unroll
    for (int i = 0; i < 4; i++)
#pragma unroll
        for (int j = 0; j < 8; j++) acc[i][j] = 0.f;

    const float* xn = x + (size_t)n * CHW * TT;

    for (int kk0 = kbeg; kk0 < kend; kk0 += KSTEP) {
        // stage x rows (32 rows x 64 t), zero-fill OOB (k tail, t tail)
#pragma unroll
        for (int l = 0; l < 8; l++) {
            int idx = l * 256 + tid;
            int r = idx >> 6;
            int col = idx & 63;
            int c = kk0 + r;
            int t = t0 + col;
            float v = (c < kend && t < TT) ? xn[(size_t)c * TT + t] : 0.f;
            xs[r][col] = v;
        }
        // stage Wt rows (32 rows x 128 o) as float4
#pragma unroll
        for (int l = 0; l < 4; l++) {
            int idx = l * 256 + tid;
            int r = idx >> 5;
            int col4 = idx & 31;
            int c = kk0 + r;
            float4 v = make_float4(0.f, 0.f, 0.f, 0.f);
            if (c < kend) v = ((const float4*)(Wt + (size_t)c * OUT))[col4];
            ((float4*)&wsm[r][0])[col4] = v;
        }
        __syncthreads();
#pragma unroll
        for (int kk = 0; kk < KSTEP; kk++) {
            float4 a  = *(const float4*)&xs[kk][ti * 4];
            float4 b0 = *(const float4*)&wsm[kk][oj * 8];
            float4 b1 = *(const float4*)&wsm[kk][oj * 8 + 4];
            float av[4] = {a.x, a.y, a.z, a.w};
            float bv[8] = {b0.x, b0.y, b0.z, b0.w, b1.x, b1.y, b1.z, b1.w};
#pragma unroll
            for (int i = 0; i < 4; i++)
#pragma unroll
                for (int j = 0; j < 8; j++) acc[i][j] += av[i] * bv[j];
        }
        __syncthreads();
    }

    // store partial tile: vp[((ks*T + t)*N + n)*OUT + o]
#pragma unroll
    for (int i = 0; i < 4; i++) {
        int t = t0 + ti * 4 + i;
        if (t < TT) {
            float* dst = vp + (((size_t)ks * TT + t) * NB + n) * OUT + oj * 8;
            float4 v0 = make_float4(acc[i][0], acc[i][1], acc[i][2], acc[i][3]);
            float4 v1 = make_float4(acc[i][4], acc[i][5], acc[i][6], acc[i][7]);
            ((float4*)dst)[0] = v0;
            ((float4*)dst)[1] = v1;
        }
    }
}

// ---------------- Kernel 3: fused alpha-filter + spike scan ----------------
// One thread per (n,o) neuron: sums 8 K-partials deterministically, runs the
// alpha recursion (commuted past the linear projection) and the refractory
// spike recursion, buffers 64 timesteps in LDS, flushes transposed (coalesced).
__global__ __launch_bounds__(64) void scanspike(const float* __restrict__ vp,
                                                float* __restrict__ out) {
    const int lane = threadIdx.x;                // 0..63
    const int gid = blockIdx.x * 64 + lane;      // 0..1023
    const int n = gid >> 7;
    const int o = gid & 127;

    const float RA = 0.9048374180359595f;        // exp(-TS/TAU_SR)
    const float CA = 0.27182818284590452f;       // (TS/TAU_SR)*e
    const float RS = 0.36787944117144233f;       // exp(-TS/TAU_REF)
    const float CS = -54.365636569180902f;       // -SCALE_REF*THETA*(TS/TAU_REF)*e
    const float THETA = 10.0f;

    __shared__ float sbuf[64][65];

    float Aa = 0.f, Ba = 0.f, As = 0.f, Bs = 0.f;

    for (int t = 0; t < TT; t++) {
        const float* p = vp + ((size_t)t * NB + n) * OUT + o;
        float vt = 0.f;
#pragma unroll
        for (int k = 0; k < KS; k++) vt += p[(size_t)k * TT * NB * OUT];

        // alpha filter step (output BEFORE update, kernel[0]=0)
        float ua = Aa;
        float Bpa = Ba + CA * vt;
        Aa = RA * (Aa + Bpa);
        Ba = RA * Bpa;

        // spike + refractory step
        float u = ua + As;
        float s = (u >= THETA) ? 1.f : 0.f;
        float Bps = Bs + CS * s;
        As = RS * (As + Bps);
        Bs = RS * Bps;

        sbuf[lane][t & 63] = s;

        if ((t & 63) == 63 || t == TT - 1) {
            __syncthreads();
            int tcnt = (t & 63) + 1;
            int tbase = t - tcnt + 1;
            // transposed flush: each row r is neuron (blockIdx*64+r); lanes cover t
            for (int r = 0; r < 64; r++) {
                int gr = blockIdx.x * 64 + r;
                int nr = gr >> 7;
                int orr = gr & 127;
                if (lane < tcnt)
                    out[((size_t)nr * OUT + orr) * TT + tbase + lane] = sbuf[r][lane];
            }
            __syncthreads();
        }
    }
}

extern "C" void kernel_launch(void* const* d_in, const int* in_sizes, int n_in,
                              void* d_out, int out_size, void* d_ws, size_t ws_size,
                              hipStream_t stream) {
    const float* x = (const float*)d_in[0];   // [N, C, H, W, T] = [8,2,50,63,500]
    const float* W = (const float*)d_in[1];   // [OUT, CHW] = [128, 6300]
    float* out = (float*)d_out;               // [N, OUT, 1, 1, T]

    float* Wt = (float*)d_ws;                                   // 6300*128*4   = 3,225,600 B
    float* vp = (float*)((char*)d_ws + (size_t)CHW * OUT * 4);  // 8*500*8*128*4 = 16,384,000 B

    transposeW<<<dim3((CHW + 31) / 32, OUT / 32), dim3(32, 8), 0, stream>>>(W, Wt);
    proj<<<dim3(8, NB, KS), 256, 0, stream>>>(x, Wt, vp);
    scanspike<<<16, 64, 0, stream>>>(vp, out);
}

// Round 2
// 187.840 us; speedup vs baseline: 1.9532x; 1.9532x over previous
//
#include <hip/hip_runtime.h>

#define NB 8
#define CHW 6300
#define TT 500
#define OUT 128
#define KS 8
#define KC 800
#define KSTEP 32
#define NO 1024   // N*OUT chains

// ---------------- Kernel 1: transpose W[OUT][CHW] -> Wt[CHW][OUT] ----------------
__global__ __launch_bounds__(256) void transposeW(const float* __restrict__ W,
                                                  float* __restrict__ Wt) {
    __shared__ float tile[32][33];
    int bc = blockIdx.x * 32;           // c base
    int bo = blockIdx.y * 32;           // o base
    int tx = threadIdx.x;               // 0..31
    int ty = threadIdx.y;               // 0..7
#pragma unroll
    for (int k = 0; k < 4; k++) {
        int o = bo + ty + k * 8;
        int c = bc + tx;
        float v = (c < CHW) ? W[(size_t)o * CHW + c] : 0.f;
        tile[ty + k * 8][tx] = v;
    }
    __syncthreads();
#pragma unroll
    for (int k = 0; k < 4; k++) {
        int c = bc + ty + k * 8;
        int o = bo + tx;
        if (c < CHW) Wt[(size_t)c * OUT + o] = tile[tx][ty + k * 8];
    }
}

// ---------------- Kernel 2: split-K projection vp[ks][t][n][o] ----------------
__global__ __launch_bounds__(256) void proj(const float* __restrict__ x,
                                            const float* __restrict__ Wt,
                                            float* __restrict__ vp) {
    const int tt = blockIdx.x;          // t tile 0..7
    const int n  = blockIdx.y;          // 0..7
    const int ks = blockIdx.z;          // 0..7
    const int t0 = tt * 64;
    const int kbeg = ks * KC;
    const int kend = min(kbeg + KC, CHW);

    __shared__ float xs[KSTEP][64];
    __shared__ float wsm[KSTEP][OUT];

    const int tid = threadIdx.x;
    const int ti = tid >> 4;            // 0..15 -> t = t0 + ti*4 + i
    const int oj = tid & 15;            // 0..15 -> o = oj*8 + j

    float acc[4][8];
#pragma unroll
    for (int i = 0; i < 4; i++)
#pragma unroll
        for (int j = 0; j < 8; j++) acc[i][j] = 0.f;

    const float* xn = x + (size_t)n * CHW * TT;

    for (int kk0 = kbeg; kk0 < kend; kk0 += KSTEP) {
#pragma unroll
        for (int l = 0; l < 8; l++) {
            int idx = l * 256 + tid;
            int r = idx >> 6;
            int col = idx & 63;
            int c = kk0 + r;
            int t = t0 + col;
            float v = (c < kend && t < TT) ? xn[(size_t)c * TT + t] : 0.f;
            xs[r][col] = v;
        }
#pragma unroll
        for (int l = 0; l < 4; l++) {
            int idx = l * 256 + tid;
            int r = idx >> 5;
            int col4 = idx & 31;
            int c = kk0 + r;
            float4 v = make_float4(0.f, 0.f, 0.f, 0.f);
            if (c < kend) v = ((const float4*)(Wt + (size_t)c * OUT))[col4];
            ((float4*)&wsm[r][0])[col4] = v;
        }
        __syncthreads();
#pragma unroll
        for (int kk = 0; kk < KSTEP; kk++) {
            float4 a  = *(const float4*)&xs[kk][ti * 4];
            float4 b0 = *(const float4*)&wsm[kk][oj * 8];
            float4 b1 = *(const float4*)&wsm[kk][oj * 8 + 4];
            float av[4] = {a.x, a.y, a.z, a.w};
            float bv[8] = {b0.x, b0.y, b0.z, b0.w, b1.x, b1.y, b1.z, b1.w};
#pragma unroll
            for (int i = 0; i < 4; i++)
#pragma unroll
                for (int j = 0; j < 8; j++) acc[i][j] += av[i] * bv[j];
        }
        __syncthreads();
    }

#pragma unroll
    for (int i = 0; i < 4; i++) {
        int t = t0 + ti * 4 + i;
        if (t < TT) {
            float* dst = vp + (((size_t)ks * TT + t) * NB + n) * OUT + oj * 8;
            ((float4*)dst)[0] = make_float4(acc[i][0], acc[i][1], acc[i][2], acc[i][3]);
            ((float4*)dst)[1] = make_float4(acc[i][4], acc[i][5], acc[i][6], acc[i][7]);
        }
    }
}

// ---------------- Kernel 3: parallel K-partial reduction ----------------
// vred[t][n][o] = sum_{k=0..7} vp[k][t][n][o]   (fixed order, deterministic)
__global__ __launch_bounds__(256) void reduceK(const float* __restrict__ vp,
                                               float* __restrict__ vred) {
    int i = blockIdx.x * 256 + threadIdx.x;      // float4 index, 128000 total
    const float4* p = (const float4*)vp;
    float4 a = p[i];
#pragma unroll
    for (int k = 1; k < KS; k++) {
        float4 b = p[(size_t)k * (TT * NB * OUT / 4) + i];
        a.x += b.x; a.y += b.y; a.z += b.z; a.w += b.w;
    }
    ((float4*)vred)[i] = a;
}

// ---------------- Kernel 4: fused alpha-filter + spike scan ----------------
// One thread per (n,o). Per 64-t block: batch-load 64 coalesced values into
// registers (single waitcnt), 64 pure-VALU recursion steps, transposed flush.
__global__ __launch_bounds__(64) void scanspike(const float* __restrict__ v,
                                                float* __restrict__ out) {
    const int lane = threadIdx.x;                // 0..63
    const int gid = blockIdx.x * 64 + lane;      // 0..1023

    const float RA = 0.9048374180359595f;        // exp(-TS/TAU_SR)
    const float CA = 0.27182818284590452f;       // (TS/TAU_SR)*e
    const float RS = 0.36787944117144233f;       // exp(-TS/TAU_REF)
    const float CS = -54.365636569180902f;       // -SCALE_REF*THETA*(TS/TAU_REF)*e
    const float THETA = 10.0f;

    __shared__ float sbuf[64][65];

    float Aa = 0.f, Ba = 0.f, As = 0.f, Bs = 0.f;

    for (int tb = 0; tb < 8; tb++) {
        const int t0 = tb * 64;
        const int cnt = (tb == 7) ? (TT - 448) : 64;   // 64,...,64,52

        float vv[64];
        if (cnt == 64) {
#pragma unroll
            for (int i = 0; i < 64; i++) vv[i] = v[(size_t)(t0 + i) * NO + gid];
#pragma unroll
            for (int i = 0; i < 64; i++) {
                float ua = Aa;
                float Bpa = Ba + CA * vv[i];
                Aa = RA * (Aa + Bpa);
                Ba = RA * Bpa;
                float u = ua + As;
                float s = (u >= THETA) ? 1.f : 0.f;
                float Bps = Bs + CS * s;
                As = RS * (As + Bps);
                Bs = RS * Bps;
                sbuf[lane][i] = s;
            }
        } else {
#pragma unroll
            for (int i = 0; i < 52; i++) vv[i] = v[(size_t)(t0 + i) * NO + gid];
#pragma unroll
            for (int i = 0; i < 52; i++) {
                float ua = Aa;
                float Bpa = Ba + CA * vv[i];
                Aa = RA * (Aa + Bpa);
                Ba = RA * Bpa;
                float u = ua + As;
                float s = (u >= THETA) ? 1.f : 0.f;
                float Bps = Bs + CS * s;
                As = RS * (As + Bps);
                Bs = RS * Bps;
                sbuf[lane][i] = s;
            }
        }
        __syncthreads();
        // transposed flush: row r = neuron (blockIdx*64+r), lanes cover t
        for (int r = 0; r < 64; r++) {
            int gr = blockIdx.x * 64 + r;
            int nr = gr >> 7;
            int orr = gr & 127;
            if (lane < cnt)
                out[((size_t)nr * OUT + orr) * TT + t0 + lane] = sbuf[r][lane];
        }
        __syncthreads();
    }
}

extern "C" void kernel_launch(void* const* d_in, const int* in_sizes, int n_in,
                              void* d_out, int out_size, void* d_ws, size_t ws_size,
                              hipStream_t stream) {
    const float* x = (const float*)d_in[0];   // [N, C, H, W, T] = [8,2,50,63,500]
    const float* W = (const float*)d_in[1];   // [OUT, CHW] = [128, 6300]
    float* out = (float*)d_out;               // [N, OUT, 1, 1, T]

    float* Wt = (float*)d_ws;                                   // 3,225,600 B (reused as vred after proj)
    float* vp = (float*)((char*)d_ws + (size_t)CHW * OUT * 4);  // 16,384,000 B
    float* vred = Wt;                                           // 2,048,000 B < Wt size; proj is done by then

    transposeW<<<dim3((CHW + 31) / 32, OUT / 32), dim3(32, 8), 0, stream>>>(W, Wt);
    proj<<<dim3(8, NB, KS), 256, 0, stream>>>(x, Wt, vp);
    reduceK<<<TT * NB * OUT / 4 / 256, 256, 0, stream>>>(vp, vred);
    scanspike<<<16, 64, 0, stream>>>(vred, out);
}